// Round 2
// baseline (17672.403 us; speedup 1.0000x reference)
//
#include <hip/hip_runtime.h>
#include <stdint.h>

// Problem: B=64, L=128, H=512, LAB=128. 8192 strictly-sequential LSTM cell
// steps sharing one (h,c) of size 512.
//   gates[s] = pre[s] + W_p @ h[s-64] + W_hh @ h[s-1]
//   pre[s]   = W_ih[:, :2048] @ [x;hi] + b_ih + b_hh     (parallel GEMM)
//
// Workspace layouts (runtime-selected on ws_size):
//   A (ws>=80MB): pre fp32 [8192][2048] (64MB) ; units u64 [8192][256] (16MB)
//   B (ws>=48MB): pre bf16-packed u32 [8192][1024] (32MB) ; units (16MB)
//   else: sentinel kernel writes 12345.0 to out (diagnostic signal).
// unit = { lo: 2 x bf16 h values, hi: step tag (s+1) }  (tagged data = flag)
// All spin loops are bounded (1e6 trips) -> sDead flag -> no container hangs.

#define HDIM   512
#define NSTEP  8192
#define GATES  2048
#define XDIM   2048
#define IN5H   2560
#define LSEQ   128
#define LAB    128
#define SPIN_LIMIT 1000000

typedef float f32x4 __attribute__((ext_vector_type(4)));
typedef short bf16x8 __attribute__((ext_vector_type(8)));

__device__ __forceinline__ unsigned f2bf(float v){
  unsigned u = __float_as_uint(v);
  u += 0x7fffu + ((u >> 16) & 1u);      // RNE; values bounded (no NaN/Inf)
  return u >> 16;
}
__device__ __forceinline__ float bf2f_lo(unsigned lo){ return __uint_as_float((lo & 0xffffu) << 16); }
__device__ __forceinline__ float bf2f_hi(unsigned lo){ return __uint_as_float(lo & 0xffff0000u); }

// ---------------------------------------------------------------- phase 1
// pre[s][r] = sum_k xcat[s][k]*W_ih[r][k] + b_ih[r] + b_hh[r]
// 128x128 tile, bf16 MFMA 16x16x32, fp32->bf16 conversion fused in staging.
// PREMODE: 0 = fp32 out, 1 = bf16-packed out.
template<int PREMODE>
__global__ __launch_bounds__(256) void gemm_pre(
    const float* __restrict__ x, const float* __restrict__ hi,
    const float* __restrict__ Wih, const float* __restrict__ bih,
    const float* __restrict__ bhh, void* __restrict__ preOut)
{
  __shared__ unsigned short As[128][40];   // +8 pad, 16B-aligned b128 reads
  __shared__ unsigned short Bs[128][40];
  const int tid = threadIdx.x;
  const int bm = blockIdx.x, bn = blockIdx.y;
  const int lane = tid & 63, wv = tid >> 6;
  const int wm = wv & 1, wn = wv >> 1;

  const int srow = tid >> 1;              // staging row 0..127
  const int ch   = (tid & 1) * 16;        // col half of the 32-wide K chunk

  const int gr = bm*128 + srow;           // global s row
  const int bb = gr & 63, tt = gr >> 6;   // s = t*64 + b
  const float* ax = x  + (size_t)(bb*LSEQ + tt) * 1024;
  const float* ah = hi + (size_t)(bb*LSEQ + tt) * 1024;
  const int R = bn*128 + srow;            // global gate row
  const float* bw = Wih + (size_t)R * IN5H;

  f32x4 acc[4][4];
  #pragma unroll
  for (int m=0;m<4;++m)
    #pragma unroll
    for (int n=0;n<4;++n) acc[m][n] = (f32x4){0.f,0.f,0.f,0.f};

  for (int kc = 0; kc < XDIM; kc += 32){
    const int c0 = kc + ch;
    const float* ap = (c0 < 1024) ? (ax + c0) : (ah + (c0 - 1024));
    #pragma unroll
    for (int q=0;q<4;++q){
      float4 va = *(const float4*)(ap + 4*q);
      float4 vb = *(const float4*)(bw + c0 + 4*q);
      ushort4 ua; ua.x=f2bf(va.x); ua.y=f2bf(va.y); ua.z=f2bf(va.z); ua.w=f2bf(va.w);
      ushort4 ub; ub.x=f2bf(vb.x); ub.y=f2bf(vb.y); ub.z=f2bf(vb.z); ub.w=f2bf(vb.w);
      *(ushort4*)&As[srow][ch + 4*q] = ua;
      *(ushort4*)&Bs[srow][ch + 4*q] = ub;
    }
    __syncthreads();
    bf16x8 afr[4], bfr[4];
    const int mr = wm*64 + (lane & 15);
    const int nr = wn*64 + (lane & 15);
    const int ko = (lane >> 4) * 8;
    #pragma unroll
    for (int m=0;m<4;++m) afr[m] = *(const bf16x8*)&As[mr + 16*m][ko];
    #pragma unroll
    for (int n=0;n<4;++n) bfr[n] = *(const bf16x8*)&Bs[nr + 16*n][ko];
    #pragma unroll
    for (int m=0;m<4;++m)
      #pragma unroll
      for (int n=0;n<4;++n)
        acc[m][n] = __builtin_amdgcn_mfma_f32_16x16x32_bf16(afr[m], bfr[n], acc[m][n], 0, 0, 0);
    __syncthreads();
  }
  // C/D layout (verified m89/m91): col = lane&15 (N side), row = (lane>>4)*4+q
  #pragma unroll
  for (int n=0;n<4;++n){
    const int scol = bn*128 + wn*64 + 16*n + (lane & 15);
    const float bias = bih[scol] + bhh[scol];
    #pragma unroll
    for (int m=0;m<4;++m){
      const int sr0 = bm*128 + wm*64 + 16*m + (lane >> 4)*4;
      #pragma unroll
      for (int q=0;q<4;++q){
        const float v = acc[m][n][q] + bias;
        if (PREMODE == 0){
          ((float*)preOut)[(size_t)(sr0 + q) * GATES + scol] = v;
        } else {
          const float vn = __shfl_xor(v, 1, 64);   // neighbor col (scol^1)
          if (!(lane & 1)){
            const unsigned word = f2bf(v) | (f2bf(vn) << 16);
            ((unsigned*)preOut)[(size_t)(sr0 + q) * 1024 + (scol >> 1)] = word;
          }
        }
      }
    }
  }
}

// ---------------------------------------------------------------- phase 2
// Persistent cooperative scan: 64 WGs x 512 threads. WG w owns h[8w..8w+8).
// Rows (row_local = gate*8 + jl, gate order i,f,g,o): wave k holds rows
// 4k..4k+3; lane l holds cols {l + 64*ci}. Weights live in VGPRs.
template<int PREMODE>
__global__ __launch_bounds__(512) void lstm_seq(
    const float* __restrict__ Wih, const float* __restrict__ Whh,
    const void* __restrict__ preOut, unsigned long long* __restrict__ units)
{
  const int tid = threadIdx.x;
  const int w = blockIdx.x;          // 0..63
  const int k = tid >> 6, l = tid & 63;

  __shared__ float hvec[512];        // h[s-1]
  __shared__ float uvec[512];        // h published at step s-63
  __shared__ float accS[32];         // h-part row sums (+accU) for this step
  __shared__ float accU[32];         // u-part row sums for next step
  __shared__ float preBuf[2][32];    // prefetched pre[s] slice
  __shared__ int   sDead;            // bailout flag (bounded spins)

  // --- load this thread's weight tile into registers (once) ---
  float wu[4][8], wh[4][8];
  #pragma unroll
  for (int i=0;i<4;++i){
    const int rl = 4*k + i;
    const int gate = rl >> 3, jl = rl & 7;
    const int R = gate*HDIM + 8*w + jl;
    const float* pu = Wih + (size_t)R*IN5H + XDIM;   // W_ih[:, 2048:2560]
    const float* ph = Whh + (size_t)R*HDIM;
    #pragma unroll
    for (int c=0;c<8;++c){ wu[i][c] = pu[l + 64*c]; wh[i][c] = ph[l + 64*c]; }
  }
  hvec[tid] = 0.f; uvec[tid] = 0.f;
  if (tid == 0) sDead = 0;
  if (tid < 32) accU[tid] = 0.f;
  if (tid >= 32 && tid < 64){
    const int rl = tid - 32;
    if (PREMODE == 0){
      preBuf[0][rl] = ((const float*)preOut)[(size_t)0*GATES + (rl >> 3)*HDIM + 8*w + (rl & 7)];
    } else if (rl < 16){
      const int g = rl >> 2, wi = rl & 3;
      const unsigned word = ((const unsigned*)preOut)[(size_t)0*1024 + g*256 + 4*w + wi];
      preBuf[0][2*rl]   = bf2f_lo(word);
      preBuf[0][2*rl+1] = bf2f_hi(word);
    }
  }
  float cst = 0.f;                   // c state (threads 0..7 own c[8w+tid])
  __syncthreads();

  for (int s = 0; s < NSTEP; ++s){
    const int dead = sDead;
    // --- stage 1: waves 0-3 poll h[s-1]; waves 4-7 fetch unit[s-63] ---
    if (!dead){
      if (k < 4){
        if (s > 0){
          const int idx = k*64 + l;                        // unit 0..255
          const unsigned long long* p = units + (size_t)(s-1)*256 + idx;
          unsigned long long v; int trips = 0; int ok;
          do {
            v = __hip_atomic_load(p, __ATOMIC_RELAXED, __HIP_MEMORY_SCOPE_AGENT);
            ok = __all((int)((unsigned)(v >> 32) == (unsigned)s));
          } while (!ok && ++trips < SPIN_LIMIT);
          if (!ok) sDead = 1;
          const unsigned lo = (unsigned)v;
          hvec[2*idx]   = bf2f_lo(lo);
          hvec[2*idx+1] = bf2f_hi(lo);
        }
      } else {
        if (s >= 63){
          const int idx = (k-4)*64 + l;
          const unsigned long long* p = units + (size_t)(s-63)*256 + idx;
          unsigned long long v; int trips = 0; int ok;
          do {
            v = __hip_atomic_load(p, __ATOMIC_RELAXED, __HIP_MEMORY_SCOPE_AGENT);
            ok = __all((int)((unsigned)(v >> 32) == (unsigned)(s-62)));
          } while (!ok && ++trips < SPIN_LIMIT);
          if (!ok) sDead = 1;
          const unsigned lo = (unsigned)v;
          uvec[2*idx]   = bf2f_lo(lo);
          uvec[2*idx+1] = bf2f_hi(lo);
        }
      }
    }
    __syncthreads();

    // --- stage 2: h-part matvec (critical path) + wave reduce ---
    {
      float a0=0.f, a1=0.f, a2=0.f, a3=0.f;
      #pragma unroll
      for (int c=0;c<8;++c){
        const float hv = hvec[l + 64*c];
        a0 += wh[0][c]*hv; a1 += wh[1][c]*hv; a2 += wh[2][c]*hv; a3 += wh[3][c]*hv;
      }
      #pragma unroll
      for (int off=32; off>=1; off>>=1){
        a0 += __shfl_xor(a0, off, 64);
        a1 += __shfl_xor(a1, off, 64);
        a2 += __shfl_xor(a2, off, 64);
        a3 += __shfl_xor(a3, off, 64);
      }
      if (l == 0){
        accS[4*k+0] = a0 + accU[4*k+0];
        accS[4*k+1] = a1 + accU[4*k+1];
        accS[4*k+2] = a2 + accU[4*k+2];
        accS[4*k+3] = a3 + accU[4*k+3];
      }
    }
    __syncthreads();

    // --- stage 3a: pointwise + publish h (lanes 0..7 of wave 0) ---
    if (tid < 8){
      const int jl = tid;
      const float* pb = preBuf[s & 1];
      float gi = accS[jl]      + pb[jl];
      float gf = accS[8 + jl]  + pb[8 + jl];
      float gg = accS[16 + jl] + pb[16 + jl];
      float go = accS[24 + jl] + pb[24 + jl];
      gi = 1.f/(1.f + __expf(-gi));
      gf = 1.f/(1.f + __expf(-gf));
      go = 1.f/(1.f + __expf(-go));
      float e2 = __expf(2.f * fminf(fmaxf(gg, -15.f), 15.f));
      gg = (e2 - 1.f) / (e2 + 1.f);
      cst = gf*cst + gi*gg;
      float e2c = __expf(2.f * fminf(fmaxf(cst, -15.f), 15.f));
      const float hval = go * ((e2c - 1.f) / (e2c + 1.f));
      const float hn = __shfl_xor(hval, 1, 64);
      if ((jl & 1) == 0){
        const unsigned lo = f2bf(hval) | (f2bf(hn) << 16);
        const unsigned long long unit =
            (unsigned long long)lo | ((unsigned long long)(unsigned)(s + 1) << 32);
        __hip_atomic_store(units + (size_t)s*256 + (4*w + (jl >> 1)), unit,
                           __ATOMIC_RELAXED, __HIP_MEMORY_SCOPE_AGENT);
      }
    }
    // --- stage 3b: u-part matvec for step s+1 (hides store->visibility) ---
    {
      float a0=0.f, a1=0.f, a2=0.f, a3=0.f;
      #pragma unroll
      for (int c=0;c<8;++c){
        const float uv = uvec[l + 64*c];
        a0 += wu[0][c]*uv; a1 += wu[1][c]*uv; a2 += wu[2][c]*uv; a3 += wu[3][c]*uv;
      }
      #pragma unroll
      for (int off=32; off>=1; off>>=1){
        a0 += __shfl_xor(a0, off, 64);
        a1 += __shfl_xor(a1, off, 64);
        a2 += __shfl_xor(a2, off, 64);
        a3 += __shfl_xor(a3, off, 64);
      }
      if (l == 0){
        accU[4*k+0] = a0; accU[4*k+1] = a1; accU[4*k+2] = a2; accU[4*k+3] = a3;
      }
    }
    // --- stage 3c: prefetch pre[s+1] slice ---
    if ((s + 1) < NSTEP && tid >= 32 && tid < 64){
      const int rl = tid - 32;
      if (PREMODE == 0){
        preBuf[(s+1) & 1][rl] =
            ((const float*)preOut)[(size_t)(s+1)*GATES + (rl >> 3)*HDIM + 8*w + (rl & 7)];
      } else if (rl < 16){
        const int g = rl >> 2, wi = rl & 3;
        const unsigned word = ((const unsigned*)preOut)[(size_t)(s+1)*1024 + g*256 + 4*w + wi];
        preBuf[(s+1) & 1][2*rl]   = bf2f_lo(word);
        preBuf[(s+1) & 1][2*rl+1] = bf2f_hi(word);
      }
    }
    __syncthreads();
  }
}

// ---------------------------------------------------------------- phase 3
// y[b][t][lab] = sum_j h[s][j] * W_fc[lab][j] + b_fc[lab],  s = t*64 + b
__global__ __launch_bounds__(256) void fc_kernel(
    const unsigned long long* __restrict__ units,
    const float* __restrict__ Wfc, const float* __restrict__ bfc,
    float* __restrict__ out)
{
  __shared__ float hbuf[8][512];
  const int tid = threadIdx.x;
  const int s0 = blockIdx.x * 8;
  #pragma unroll
  for (int r=0;r<8;++r){
    const int q = tid + 256*r;                 // 0..2047
    const int si = q >> 8, u = q & 255;
    const unsigned lo = (unsigned)units[(size_t)(s0 + si)*256 + u];
    hbuf[si][2*u]   = bf2f_lo(lo);
    hbuf[si][2*u+1] = bf2f_hi(lo);
  }
  __syncthreads();
  const int lab = tid & 127, sg = tid >> 7;
  const float* wrow = Wfc + (size_t)lab * HDIM;
  const float bias = bfc[lab];
  for (int si = sg; si < 8; si += 2){
    float sum = 0.f;
    #pragma unroll 4
    for (int j=0;j<HDIM;j+=4){
      const float4 wv = *(const float4*)(wrow + j);
      sum += wv.x*hbuf[si][j] + wv.y*hbuf[si][j+1]
           + wv.z*hbuf[si][j+2] + wv.w*hbuf[si][j+3];
    }
    const int s = s0 + si;
    const int bb = s & 63, tt = s >> 6;
    out[((size_t)(bb*LSEQ + tt))*LAB + lab] = sum + bias;
  }
}

__global__ void sentinel_kernel(float* out, int n){
  const int i = blockIdx.x*256 + threadIdx.x;
  if (i < n) out[i] = 12345.0f;     // diagnostic: ws_size too small
}

extern "C" void kernel_launch(void* const* d_in, const int* in_sizes, int n_in,
                              void* d_out, int out_size, void* d_ws, size_t ws_size,
                              hipStream_t stream)
{
  const float* x   = (const float*)d_in[0];
  const float* hi  = (const float*)d_in[1];
  const float* Wih = (const float*)d_in[2];
  const float* Whh = (const float*)d_in[3];
  const float* bih = (const float*)d_in[4];
  const float* bhh = (const float*)d_in[5];
  const float* Wfc = (const float*)d_in[6];
  const float* bfc = (const float*)d_in[7];
  float* out = (float*)d_out;

  const size_t MB = 1024*1024;
  if (ws_size >= 80*MB){
    void* pre = d_ws;                                               // 64MB fp32
    unsigned long long* units =
        (unsigned long long*)((char*)d_ws + 64*MB);                 // 16MB
    gemm_pre<0><<<dim3(64, 16), 256, 0, stream>>>(x, hi, Wih, bih, bhh, pre);
    lstm_seq<0><<<64, 512, 0, stream>>>(Wih, Whh, pre, units);
    fc_kernel<<<1024, 256, 0, stream>>>(units, Wfc, bfc, out);
  } else if (ws_size >= 48*MB){
    void* pre = d_ws;                                               // 32MB bf16
    unsigned long long* units =
        (unsigned long long*)((char*)d_ws + 32*MB);                 // 16MB
    gemm_pre<1><<<dim3(64, 16), 256, 0, stream>>>(x, hi, Wih, bih, bhh, pre);
    lstm_seq<1><<<64, 512, 0, stream>>>(Wih, Whh, pre, units);
    fc_kernel<<<1024, 256, 0, stream>>>(units, Wfc, bfc, out);
  } else {
    sentinel_kernel<<<(out_size + 255)/256, 256, 0, stream>>>(out, out_size);
  }
}